// Round 1
// baseline (444.697 us; speedup 1.0000x reference)
//
#include <hip/hip_runtime.h>

#define NN 50000
#define NE 600000
#define FIN 64
#define FHID 128
#define BN_EPS 1e-5f

// ---------------- edge counting ----------------
__global__ __launch_bounds__(256) void count_kernel(const int* __restrict__ dst,
                                                    int* __restrict__ cnt) {
  int e = blockIdx.x * 256 + threadIdx.x;
  if (e < NE) atomicAdd(&cnt[dst[e]], 1);
}

// ---------------- exclusive scan over cnt (3 kernels) ----------------
__global__ __launch_bounds__(256) void scan1(const int* __restrict__ cnt,
                                             int* __restrict__ partial) {
  int i = blockIdx.x * 256 + threadIdx.x;
  int v = (i < NN) ? cnt[i] : 0;
  __shared__ int sh[256];
  sh[threadIdx.x] = v;
  __syncthreads();
  for (int off = 128; off > 0; off >>= 1) {
    if (threadIdx.x < off) sh[threadIdx.x] += sh[threadIdx.x + off];
    __syncthreads();
  }
  if (threadIdx.x == 0) partial[blockIdx.x] = sh[0];
}

__global__ __launch_bounds__(256) void scan2(int* __restrict__ partial, int nb) {
  __shared__ int sh[256];
  int t = threadIdx.x;
  sh[t] = (t < nb) ? partial[t] : 0;
  __syncthreads();
  for (int off = 1; off < 256; off <<= 1) {
    int v = (t >= off) ? sh[t - off] : 0;
    __syncthreads();
    sh[t] += v;
    __syncthreads();
  }
  partial[t] = (t == 0) ? 0 : sh[t - 1];  // exclusive
}

__global__ __launch_bounds__(256) void scan3(const int* __restrict__ cnt,
                                             const int* __restrict__ partial,
                                             int* __restrict__ rowptr,
                                             float* __restrict__ dis) {
  int i = blockIdx.x * 256 + threadIdx.x;
  int t = threadIdx.x;
  int v = (i < NN) ? cnt[i] : 0;
  __shared__ int sh[256];
  sh[t] = v;
  __syncthreads();
  for (int off = 1; off < 256; off <<= 1) {
    int u = (t >= off) ? sh[t - off] : 0;
    __syncthreads();
    sh[t] += u;
    __syncthreads();
  }
  if (i < NN) {
    rowptr[i] = partial[blockIdx.x] + (sh[t] - v);
    dis[i] = rsqrtf((float)(v + 1));  // deg = indeg + 1 (self loop); always >0
  }
}

// ---------------- CSR bucket fill ----------------
__global__ __launch_bounds__(256) void fill_kernel(const int* __restrict__ src,
                                                   const int* __restrict__ dst,
                                                   const int* __restrict__ rowptr,
                                                   int* __restrict__ fill,
                                                   int* __restrict__ csr_src) {
  int e = blockIdx.x * 256 + threadIdx.x;
  if (e < NE) {
    int d = dst[e];
    int p = atomicAdd(&fill[d], 1);
    csr_src[rowptr[d] + p] = src[e];
  }
}

// ---------------- GCN aggregation on raw X (64 feats), one wave per node ----
__global__ __launch_bounds__(256) void gcn_agg(const float* __restrict__ x,
                                               const int* __restrict__ csr_src,
                                               const int* __restrict__ rowptr,
                                               const int* __restrict__ cnt,
                                               const float* __restrict__ dis,
                                               float* __restrict__ xa) {
  int node = blockIdx.x * 4 + threadIdx.y;
  int lane = threadIdx.x;
  float di = dis[node];
  float acc = di * di * x[node * FIN + lane];  // self loop: dis[i]^2
  int beg = rowptr[node];
  int num = cnt[node];
  for (int e = 0; e < num; ++e) {
    int s = csr_src[beg + e];
    acc += di * dis[s] * x[s * FIN + lane];
  }
  xa[node * FIN + lane] = acc;
}

// ---------------- SAGE mean aggregation (128 feats), one wave per node ------
__global__ __launch_bounds__(256) void sage_agg(const float* __restrict__ h,
                                                const int* __restrict__ csr_src,
                                                const int* __restrict__ rowptr,
                                                const int* __restrict__ cnt,
                                                float* __restrict__ neigh) {
  int node = blockIdx.x * 4 + threadIdx.y;
  int lane = threadIdx.x;
  float2 acc = make_float2(0.f, 0.f);
  int beg = rowptr[node];
  int num = cnt[node];
  for (int e = 0; e < num; ++e) {
    int s = csr_src[beg + e];
    float2 v = *(const float2*)&h[s * FHID + lane * 2];
    acc.x += v.x;
    acc.y += v.y;
  }
  float inv = 1.0f / fmaxf((float)num, 1.0f);
  float2 o = make_float2(acc.x * inv, acc.y * inv);
  *(float2*)&neigh[node * FHID + lane * 2] = o;
}

// ---------------- fp32 tiled GEMM: C[NN,128] = A1@B1 (+ A2@B2) + bias -------
// block: 256 threads; tile 64 rows x 128 cols; per-thread 4x8 accumulators.
template <int K1, int K2>
__global__ __launch_bounds__(256) void gemm_kernel(const float* __restrict__ A1,
                                                   const float* __restrict__ B1,
                                                   const float* __restrict__ A2,
                                                   const float* __restrict__ B2,
                                                   const float* __restrict__ bias,
                                                   float* __restrict__ C) {
  __shared__ float As[64][68];   // +4 pad: breaks stride-64 bank aliasing
  __shared__ float Bs[64][128];
  int t = threadIdx.x;
  int tcol = t & 15;    // 16 col groups * 8 cols
  int trow = t >> 4;    // 16 row groups * 4 rows
  int row0 = blockIdx.x * 64;

  float acc[4][8];
#pragma unroll
  for (int i = 0; i < 4; ++i)
#pragma unroll
    for (int j = 0; j < 8; ++j) acc[i][j] = 0.f;

#pragma unroll
  for (int p = 0; p < 2; ++p) {
    const float* A = p ? A2 : A1;
    const float* B = p ? B2 : B1;
    const int K = p ? K2 : K1;
    if (K == 0) break;
    for (int kc = 0; kc < K; kc += 64) {
      // stage A 64x64 (1024 float4, 4 per thread)
#pragma unroll
      for (int q = t; q < 1024; q += 256) {
        int r = q >> 4, c4 = q & 15;
        float4 v = make_float4(0.f, 0.f, 0.f, 0.f);
        if (row0 + r < NN)
          v = *(const float4*)&A[(size_t)(row0 + r) * K + kc + c4 * 4];
        *(float4*)&As[r][c4 * 4] = v;
      }
      // stage B 64x128 (2048 float4, 8 per thread)
#pragma unroll
      for (int q = t; q < 2048; q += 256) {
        int r = q >> 5, c4 = q & 31;
        *(float4*)&Bs[r][c4 * 4] = *(const float4*)&B[(size_t)(kc + r) * 128 + c4 * 4];
      }
      __syncthreads();
#pragma unroll 8
      for (int k = 0; k < 64; ++k) {
        float a[4];
#pragma unroll
        for (int i = 0; i < 4; ++i) a[i] = As[trow * 4 + i][k];
        float4 b0 = *(const float4*)&Bs[k][tcol * 8];
        float4 b1 = *(const float4*)&Bs[k][tcol * 8 + 4];
        float b[8] = {b0.x, b0.y, b0.z, b0.w, b1.x, b1.y, b1.z, b1.w};
#pragma unroll
        for (int i = 0; i < 4; ++i)
#pragma unroll
          for (int j = 0; j < 8; ++j) acc[i][j] += a[i] * b[j];
      }
      __syncthreads();
    }
  }

  // epilogue: + bias, store
  float bb[8];
#pragma unroll
  for (int j = 0; j < 8; ++j) bb[j] = bias[tcol * 8 + j];
#pragma unroll
  for (int i = 0; i < 4; ++i) {
    int row = row0 + trow * 4 + i;
    if (row < NN) {
      float4 o0, o1;
      o0.x = acc[i][0] + bb[0]; o0.y = acc[i][1] + bb[1];
      o0.z = acc[i][2] + bb[2]; o0.w = acc[i][3] + bb[3];
      o1.x = acc[i][4] + bb[4]; o1.y = acc[i][5] + bb[5];
      o1.z = acc[i][6] + bb[6]; o1.w = acc[i][7] + bb[7];
      *(float4*)&C[(size_t)row * 128 + tcol * 8] = o0;
      *(float4*)&C[(size_t)row * 128 + tcol * 8 + 4] = o1;
    }
  }
}

// ---------------- BatchNorm: column sums / sumsq ----------------
__global__ __launch_bounds__(256) void bn_stats(const float* __restrict__ h,
                                                float* __restrict__ sums,
                                                float* __restrict__ sumsq) {
  int f = threadIdx.x & 127;
  int half = threadIdx.x >> 7;
  float s = 0.f, q = 0.f;
  for (int n = blockIdx.x * 2 + half; n < NN; n += gridDim.x * 2) {
    float v = h[(size_t)n * 128 + f];
    s += v;
    q += v * v;
  }
  __shared__ float ss[128], sq[128];
  if (half == 0) { ss[f] = s; sq[f] = q; }
  __syncthreads();
  if (half == 1) {
    atomicAdd(&sums[f], s + ss[f]);
    atomicAdd(&sumsq[f], q + sq[f]);
  }
}

__global__ __launch_bounds__(128) void bn_final(const float* __restrict__ sums,
                                                const float* __restrict__ sumsq,
                                                const float* __restrict__ gamma,
                                                const float* __restrict__ beta,
                                                float* __restrict__ scale,
                                                float* __restrict__ shift) {
  int f = threadIdx.x;
  float mean = sums[f] * (1.0f / NN);
  float var = sumsq[f] * (1.0f / NN) - mean * mean;
  var = fmaxf(var, 0.f);
  float inv = rsqrtf(var + BN_EPS);
  float sc = gamma[f] * inv;
  scale[f] = sc;
  shift[f] = beta[f] - mean * sc;
}

// ---------------- fused BN scale/shift + ReLU (elementwise, float4) ---------
__global__ __launch_bounds__(256) void bn_apply(const float* __restrict__ in,
                                                const float* __restrict__ scale,
                                                const float* __restrict__ shift,
                                                float* __restrict__ out) {
  int i4 = blockIdx.x * 256 + threadIdx.x;  // float4 index; grid sized exactly
  float4 v = ((const float4*)in)[i4];
  int f = (i4 & 31) * 4;  // 32 float4 per 128-wide row
  v.x = fmaxf(fmaf(v.x, scale[f + 0], shift[f + 0]), 0.f);
  v.y = fmaxf(fmaf(v.y, scale[f + 1], shift[f + 1]), 0.f);
  v.z = fmaxf(fmaf(v.z, scale[f + 2], shift[f + 2]), 0.f);
  v.w = fmaxf(fmaf(v.w, scale[f + 3], shift[f + 3]), 0.f);
  ((float4*)out)[i4] = v;
}

extern "C" void kernel_launch(void* const* d_in, const int* in_sizes, int n_in,
                              void* d_out, int out_size, void* d_ws, size_t ws_size,
                              hipStream_t stream) {
  const float* x   = (const float*)d_in[0];
  const int*   ei  = (const int*)d_in[1];
  const float* W1  = (const float*)d_in[2];
  const float* b1  = (const float*)d_in[3];
  const float* g1  = (const float*)d_in[4];
  const float* be1 = (const float*)d_in[5];
  const float* Wl  = (const float*)d_in[6];
  const float* bl  = (const float*)d_in[7];
  const float* Wr  = (const float*)d_in[8];
  const float* g2  = (const float*)d_in[9];
  const float* be2 = (const float*)d_in[10];
  const int* srcp = ei;
  const int* dstp = ei + NE;

  char* w = (char*)d_ws;
  auto alloc = [&](size_t bytes) {
    char* p = w;
    w += (bytes + 255) & ~(size_t)255;
    return p;
  };
  int*   cnt     = (int*)alloc((size_t)NN * 4);
  int*   fill    = (int*)alloc((size_t)NN * 4);
  int*   rowptr  = (int*)alloc((size_t)NN * 4);
  int*   partial = (int*)alloc(256 * 4);
  float* dis     = (float*)alloc((size_t)NN * 4);
  int*   csr     = (int*)alloc((size_t)NE * 4);
  float* xa      = (float*)alloc((size_t)NN * FIN * 4);
  float* h       = (float*)alloc((size_t)NN * FHID * 4);
  float* neigh   = (float*)alloc((size_t)NN * FHID * 4);
  float* stats   = (float*)alloc(8 * 128 * 4);
  float* sums1 = stats,        *sumsq1 = stats + 128;
  float* scale1 = stats + 256, *shift1 = stats + 384;
  float* sums2 = stats + 512,  *sumsq2 = stats + 640;
  float* scale2 = stats + 768, *shift2 = stats + 896;

  hipMemsetAsync(cnt, 0, (size_t)NN * 4, stream);
  hipMemsetAsync(fill, 0, (size_t)NN * 4, stream);
  hipMemsetAsync(stats, 0, 8 * 128 * 4, stream);

  int nbE = (NE + 255) / 256;
  int nbN = (NN + 255) / 256;  // 196 <= 256 (scan2 single-block limit)

  count_kernel<<<nbE, 256, 0, stream>>>(dstp, cnt);
  scan1<<<nbN, 256, 0, stream>>>(cnt, partial);
  scan2<<<1, 256, 0, stream>>>(partial, nbN);
  scan3<<<nbN, 256, 0, stream>>>(cnt, partial, rowptr, dis);
  fill_kernel<<<nbE, 256, 0, stream>>>(srcp, dstp, rowptr, fill, csr);

  // GCN: aggregate X (64 feats) first, then GEMM (agg commutes with W)
  gcn_agg<<<NN / 4, dim3(64, 4), 0, stream>>>(x, csr, rowptr, cnt, dis, xa);
  gemm_kernel<64, 0><<<(NN + 63) / 64, 256, 0, stream>>>(xa, W1, nullptr, nullptr, b1, h);
  bn_stats<<<512, 256, 0, stream>>>(h, sums1, sumsq1);
  bn_final<<<1, 128, 0, stream>>>(sums1, sumsq1, g1, be1, scale1, shift1);
  bn_apply<<<(NN * FHID / 4) / 256, 256, 0, stream>>>(h, scale1, shift1, h);

  // SAGE: mean-aggregate h, then fused K=256 GEMM (neigh@Wl + h@Wr + bl)
  sage_agg<<<NN / 4, dim3(64, 4), 0, stream>>>(h, csr, rowptr, cnt, neigh);
  gemm_kernel<128, 128><<<(NN + 63) / 64, 256, 0, stream>>>(neigh, Wl, h, Wr, bl,
                                                            (float*)d_out);
  bn_stats<<<512, 256, 0, stream>>>((float*)d_out, sums2, sumsq2);
  bn_final<<<1, 128, 0, stream>>>(sums2, sumsq2, g2, be2, scale2, shift2);
  bn_apply<<<(NN * FHID / 4) / 256, 256, 0, stream>>>((float*)d_out, scale2, shift2,
                                                      (float*)d_out);
}

// Round 2
// 352.649 us; speedup vs baseline: 1.2610x; 1.2610x over previous
//
#include <hip/hip_runtime.h>

#define NN 50000
#define NE 600000
#define FIN 64
#define FHID 128
#define BN_EPS 1e-5f

typedef __attribute__((ext_vector_type(8))) short short8;
typedef __attribute__((ext_vector_type(4))) float f32x4;

// ---- bf16 helpers (finite inputs; RNE) ----
__device__ __forceinline__ unsigned short f2bf(float f) {
  unsigned u = __float_as_uint(f);
  return (unsigned short)((u + 0x7FFFu + ((u >> 16) & 1u)) >> 16);
}
__device__ __forceinline__ float bfs(unsigned short u) {  // scalar bf16 -> f32
  return __uint_as_float(((unsigned)u) << 16);
}
__device__ __forceinline__ float bflo(unsigned v) { return __uint_as_float(v << 16); }
__device__ __forceinline__ float bfhi(unsigned v) { return __uint_as_float(v & 0xFFFF0000u); }

// ---------------- x fp32 -> bf16 ----------------
__global__ __launch_bounds__(256) void convert_x(const float* __restrict__ x,
                                                 ushort4* __restrict__ xb) {
  int i = blockIdx.x * 256 + threadIdx.x;  // float4 index; grid exact (800000)
  float4 v = ((const float4*)x)[i];
  xb[i] = make_ushort4(f2bf(v.x), f2bf(v.y), f2bf(v.z), f2bf(v.w));
}

// ---------------- edge counting ----------------
__global__ __launch_bounds__(256) void count_kernel(const int* __restrict__ dst,
                                                    int* __restrict__ cnt) {
  int e = blockIdx.x * 256 + threadIdx.x;
  if (e < NE) atomicAdd(&cnt[dst[e]], 1);
}

// ---------------- exclusive scan over cnt (3 kernels) ----------------
__global__ __launch_bounds__(256) void scan1(const int* __restrict__ cnt,
                                             int* __restrict__ partial) {
  int i = blockIdx.x * 256 + threadIdx.x;
  int v = (i < NN) ? cnt[i] : 0;
  __shared__ int sh[256];
  sh[threadIdx.x] = v;
  __syncthreads();
  for (int off = 128; off > 0; off >>= 1) {
    if (threadIdx.x < off) sh[threadIdx.x] += sh[threadIdx.x + off];
    __syncthreads();
  }
  if (threadIdx.x == 0) partial[blockIdx.x] = sh[0];
}

__global__ __launch_bounds__(256) void scan2(int* __restrict__ partial, int nb) {
  __shared__ int sh[256];
  int t = threadIdx.x;
  sh[t] = (t < nb) ? partial[t] : 0;
  __syncthreads();
  for (int off = 1; off < 256; off <<= 1) {
    int v = (t >= off) ? sh[t - off] : 0;
    __syncthreads();
    sh[t] += v;
    __syncthreads();
  }
  partial[t] = (t == 0) ? 0 : sh[t - 1];  // exclusive
}

__global__ __launch_bounds__(256) void scan3(const int* __restrict__ cnt,
                                             const int* __restrict__ partial,
                                             int* __restrict__ rowptr,
                                             float* __restrict__ dis) {
  int i = blockIdx.x * 256 + threadIdx.x;
  int t = threadIdx.x;
  int v = (i < NN) ? cnt[i] : 0;
  __shared__ int sh[256];
  sh[t] = v;
  __syncthreads();
  for (int off = 1; off < 256; off <<= 1) {
    int u = (t >= off) ? sh[t - off] : 0;
    __syncthreads();
    sh[t] += u;
    __syncthreads();
  }
  if (i < NN) {
    rowptr[i] = partial[blockIdx.x] + (sh[t] - v);
    dis[i] = rsqrtf((float)(v + 1));  // deg = indeg + 1 (self loop)
  }
}

// ---------------- CSR bucket fill ----------------
__global__ __launch_bounds__(256) void fill_kernel(const int* __restrict__ src,
                                                   const int* __restrict__ dst,
                                                   const int* __restrict__ rowptr,
                                                   int* __restrict__ fill,
                                                   int* __restrict__ csr_src) {
  int e = blockIdx.x * 256 + threadIdx.x;
  if (e < NE) {
    int d = dst[e];
    int p = atomicAdd(&fill[d], 1);
    csr_src[rowptr[d] + p] = src[e];
  }
}

// ---------------- GCN aggregation on bf16 X (64 feats), one wave per node ---
__global__ __launch_bounds__(256) void gcn_agg(const unsigned short* __restrict__ xb,
                                               const int* __restrict__ csr_src,
                                               const int* __restrict__ rowptr,
                                               const int* __restrict__ cnt,
                                               const float* __restrict__ dis,
                                               unsigned short* __restrict__ xa) {
  int node = blockIdx.x * 4 + threadIdx.y;
  int lane = threadIdx.x;
  float di = dis[node];
  float acc = di * di * bfs(xb[node * FIN + lane]);  // self loop: dis[i]^2
  int beg = rowptr[node];
  int num = cnt[node];
  for (int e = 0; e < num; ++e) {
    int s = csr_src[beg + e];
    acc += di * dis[s] * bfs(xb[s * FIN + lane]);
  }
  xa[node * FIN + lane] = f2bf(acc);
}

// ---------------- SAGE mean aggregation on bf16 h (128 feats) ---------------
__global__ __launch_bounds__(256) void sage_agg(const unsigned* __restrict__ hb,
                                                const int* __restrict__ csr_src,
                                                const int* __restrict__ rowptr,
                                                const int* __restrict__ cnt,
                                                unsigned* __restrict__ neighb) {
  int node = blockIdx.x * 4 + threadIdx.y;
  int lane = threadIdx.x;  // 2 feats per lane (1 uint = 2 bf16)
  float ax = 0.f, ay = 0.f;
  int beg = rowptr[node];
  int num = cnt[node];
  for (int e = 0; e < num; ++e) {
    int s = csr_src[beg + e];
    unsigned v = hb[s * 64 + lane];
    ax += bflo(v);
    ay += bfhi(v);
  }
  float inv = 1.0f / fmaxf((float)num, 1.0f);
  neighb[node * 64 + lane] =
      (unsigned)f2bf(ax * inv) | ((unsigned)f2bf(ay * inv) << 16);
}

// ---------------- MFMA bf16 GEMM, fused bias + BN column stats --------------
// C[NN,128] = A1[NN,K1]@B1[K1,128] (+ A2[NN,K2]@B2[K2,128]) + bias
// Block: 256 thr (4 waves), 128 rows; wave = 32 rows x 128 cols
// (2 m-tiles x 8 n-tiles of 16x16x32 MFMA). A-frags straight from global;
// B transposed bf16 into LDS (stride KT+8 -> 2-way bank alias = free).
template <int K1, int K2, bool OUTBF>
__global__ __launch_bounds__(256) void gemm_mfma(const short* __restrict__ A1,
                                                 const short* __restrict__ A2,
                                                 const float* __restrict__ B1,
                                                 const float* __restrict__ B2,
                                                 const float* __restrict__ bias,
                                                 float* __restrict__ Cf,
                                                 unsigned short* __restrict__ Cb,
                                                 float* __restrict__ sums,
                                                 float* __restrict__ sumsq) {
  constexpr int KT = K1 + K2;
  __shared__ short Bt[128][KT + 8];
  __shared__ float lsum[128], lsq[128];
  int tid = threadIdx.x;
  if (tid < 128) { lsum[tid] = 0.f; lsq[tid] = 0.f; }
  // stage + transpose + bf16-convert B (weights are tiny; L2-resident)
  for (int idx = tid; idx < KT * 128; idx += 256) {
    int k = idx >> 7, n = idx & 127;
    float wv = (K2 == 0 || k < K1) ? B1[k * 128 + n] : B2[(k - K1) * 128 + n];
    Bt[n][k] = (short)f2bf(wv);
  }
  __syncthreads();

  int lane = tid & 63;
  int w = tid >> 6;
  int r = lane & 15;   // row-in-tile for A/B frags; col for C frags
  int q = lane >> 4;   // k-quad
  int row_base = blockIdx.x * 128 + w * 32;

  f32x4 acc[2][8];
#pragma unroll
  for (int m = 0; m < 2; ++m)
#pragma unroll
    for (int n = 0; n < 8; ++n) acc[m][n] = (f32x4){0.f, 0.f, 0.f, 0.f};

#pragma unroll
  for (int seg = 0; seg < 2; ++seg) {
    const int K = seg ? K2 : K1;
    if (K == 0) continue;
    const short* A = seg ? A2 : A1;
    const int kb = seg ? K1 : 0;
    for (int ks = 0; ks < K; ks += 32) {
      int row0 = row_base + r;
      int row1 = row_base + 16 + r;
      row0 = row0 < NN ? row0 : NN - 1;  // clamp: garbage rows never stored
      row1 = row1 < NN ? row1 : NN - 1;
      short8 af0 = *(const short8*)(A + (size_t)row0 * K + ks + q * 8);
      short8 af1 = *(const short8*)(A + (size_t)row1 * K + ks + q * 8);
#pragma unroll
      for (int n = 0; n < 8; ++n) {
        short8 bf = *(const short8*)(&Bt[n * 16 + r][kb + ks + q * 8]);
        acc[0][n] = __builtin_amdgcn_mfma_f32_16x16x32_bf16(af0, bf, acc[0][n], 0, 0, 0);
        acc[1][n] = __builtin_amdgcn_mfma_f32_16x16x32_bf16(af1, bf, acc[1][n], 0, 0, 0);
      }
    }
  }

  // epilogue: + bias, store, per-lane column partial stats
  float bias_r[8];
#pragma unroll
  for (int n = 0; n < 8; ++n) bias_r[n] = bias[n * 16 + r];
  float cs[8], cq[8];
#pragma unroll
  for (int n = 0; n < 8; ++n) { cs[n] = 0.f; cq[n] = 0.f; }
#pragma unroll
  for (int m = 0; m < 2; ++m)
#pragma unroll
    for (int i = 0; i < 4; ++i) {
      int row = row_base + m * 16 + q * 4 + i;
      if (row < NN) {
#pragma unroll
        for (int n = 0; n < 8; ++n) {
          float v = acc[m][n][i] + bias_r[n];
          int col = n * 16 + r;
          if constexpr (OUTBF)
            Cb[(size_t)row * 128 + col] = f2bf(v);
          else
            Cf[(size_t)row * 128 + col] = v;
          cs[n] += v;
          cq[n] += v * v;
        }
      }
    }
#pragma unroll
  for (int n = 0; n < 8; ++n) {
    atomicAdd(&lsum[n * 16 + r], cs[n]);
    atomicAdd(&lsq[n * 16 + r], cq[n]);
  }
  __syncthreads();
  if (tid < 128) {
    atomicAdd(&sums[tid], lsum[tid]);
    atomicAdd(&sumsq[tid], lsq[tid]);
  }
}

// ---------------- BN finalize: scale/shift from sums ----------------
__global__ __launch_bounds__(128) void bn_final(const float* __restrict__ sums,
                                                const float* __restrict__ sumsq,
                                                const float* __restrict__ gamma,
                                                const float* __restrict__ beta,
                                                float* __restrict__ scale,
                                                float* __restrict__ shift) {
  int f = threadIdx.x;
  float mean = sums[f] * (1.0f / NN);
  float var = sumsq[f] * (1.0f / NN) - mean * mean;
  var = fmaxf(var, 0.f);
  float inv = rsqrtf(var + BN_EPS);
  float sc = gamma[f] * inv;
  scale[f] = sc;
  shift[f] = beta[f] - mean * sc;
}

// ---------------- BN apply + ReLU, bf16 in-place (4 bf16/thread) ------------
__global__ __launch_bounds__(256) void bn_apply_bf(unsigned* __restrict__ hb,
                                                   const float* __restrict__ scale,
                                                   const float* __restrict__ shift) {
  int i = blockIdx.x * 256 + threadIdx.x;  // uint2 index; grid exact
  uint2 v = ((uint2*)hb)[i];
  int c = (i & 31) * 4;  // 32 uint2 per 128-col row
  float f0 = fmaxf(fmaf(bflo(v.x), scale[c + 0], shift[c + 0]), 0.f);
  float f1 = fmaxf(fmaf(bfhi(v.x), scale[c + 1], shift[c + 1]), 0.f);
  float f2 = fmaxf(fmaf(bflo(v.y), scale[c + 2], shift[c + 2]), 0.f);
  float f3 = fmaxf(fmaf(bfhi(v.y), scale[c + 3], shift[c + 3]), 0.f);
  v.x = (unsigned)f2bf(f0) | ((unsigned)f2bf(f1) << 16);
  v.y = (unsigned)f2bf(f2) | ((unsigned)f2bf(f3) << 16);
  ((uint2*)hb)[i] = v;
}

// ---------------- BN apply + ReLU, fp32 in-place (float4/thread) ------------
__global__ __launch_bounds__(256) void bn_apply_f32(float* __restrict__ out,
                                                    const float* __restrict__ scale,
                                                    const float* __restrict__ shift) {
  int i4 = blockIdx.x * 256 + threadIdx.x;  // float4 index; grid exact
  float4 v = ((const float4*)out)[i4];
  int f = (i4 & 31) * 4;
  v.x = fmaxf(fmaf(v.x, scale[f + 0], shift[f + 0]), 0.f);
  v.y = fmaxf(fmaf(v.y, scale[f + 1], shift[f + 1]), 0.f);
  v.z = fmaxf(fmaf(v.z, scale[f + 2], shift[f + 2]), 0.f);
  v.w = fmaxf(fmaf(v.w, scale[f + 3], shift[f + 3]), 0.f);
  ((float4*)out)[i4] = v;
}

extern "C" void kernel_launch(void* const* d_in, const int* in_sizes, int n_in,
                              void* d_out, int out_size, void* d_ws, size_t ws_size,
                              hipStream_t stream) {
  const float* x   = (const float*)d_in[0];
  const int*   ei  = (const int*)d_in[1];
  const float* W1  = (const float*)d_in[2];
  const float* b1  = (const float*)d_in[3];
  const float* g1  = (const float*)d_in[4];
  const float* be1 = (const float*)d_in[5];
  const float* Wl  = (const float*)d_in[6];
  const float* bl  = (const float*)d_in[7];
  const float* Wr  = (const float*)d_in[8];
  const float* g2  = (const float*)d_in[9];
  const float* be2 = (const float*)d_in[10];
  const int* srcp = ei;
  const int* dstp = ei + NE;

  char* w = (char*)d_ws;
  auto alloc = [&](size_t bytes) {
    char* p = w;
    w += (bytes + 255) & ~(size_t)255;
    return p;
  };
  int*   cnt     = (int*)alloc((size_t)NN * 4);
  int*   fill    = (int*)alloc((size_t)NN * 4);
  int*   rowptr  = (int*)alloc((size_t)NN * 4);
  int*   partial = (int*)alloc(256 * 4);
  float* dis     = (float*)alloc((size_t)NN * 4);
  int*   csr     = (int*)alloc((size_t)NE * 4);
  unsigned short* xb     = (unsigned short*)alloc((size_t)NN * FIN * 2);   // 6.4 MB
  unsigned short* xa     = (unsigned short*)alloc((size_t)NN * FIN * 2);   // 6.4 MB
  unsigned short* hb     = (unsigned short*)alloc((size_t)NN * FHID * 2);  // 12.8 MB
  unsigned*       neighb = (unsigned*)alloc((size_t)NN * FHID * 2);        // 12.8 MB
  float* stats   = (float*)alloc(8 * 128 * 4);
  float* sums1 = stats,        *sumsq1 = stats + 128;
  float* scale1 = stats + 256, *shift1 = stats + 384;
  float* sums2 = stats + 512,  *sumsq2 = stats + 640;
  float* scale2 = stats + 768, *shift2 = stats + 896;

  hipMemsetAsync(cnt, 0, (size_t)NN * 4, stream);
  hipMemsetAsync(fill, 0, (size_t)NN * 4, stream);
  hipMemsetAsync(stats, 0, 8 * 128 * 4, stream);

  int nbE = (NE + 255) / 256;
  int nbN = (NN + 255) / 256;  // 196 <= 256 (scan2 single-block limit)
  int nbG = (NN + 127) / 128;  // 391 MFMA blocks

  convert_x<<<NN * FIN / 4 / 256, 256, 0, stream>>>(x, (ushort4*)xb);
  count_kernel<<<nbE, 256, 0, stream>>>(dstp, cnt);
  scan1<<<nbN, 256, 0, stream>>>(cnt, partial);
  scan2<<<1, 256, 0, stream>>>(partial, nbN);
  scan3<<<nbN, 256, 0, stream>>>(cnt, partial, rowptr, dis);
  fill_kernel<<<nbE, 256, 0, stream>>>(srcp, dstp, rowptr, fill, csr);

  // GCN: aggregate bf16 X (agg commutes with W), MFMA GEMM K=64 -> bf16 h
  gcn_agg<<<NN / 4, dim3(64, 4), 0, stream>>>(xb, csr, rowptr, cnt, dis, xa);
  gemm_mfma<64, 0, true><<<nbG, 256, 0, stream>>>(
      (const short*)xa, nullptr, W1, nullptr, b1, nullptr, hb, sums1, sumsq1);
  bn_final<<<1, 128, 0, stream>>>(sums1, sumsq1, g1, be1, scale1, shift1);
  bn_apply_bf<<<NN * FHID / 4 / 256, 256, 0, stream>>>((unsigned*)hb, scale1, shift1);

  // SAGE: mean-agg bf16 h, fused K=256 MFMA GEMM -> fp32 d_out
  sage_agg<<<NN / 4, dim3(64, 4), 0, stream>>>((const unsigned*)hb, csr, rowptr, cnt,
                                               neighb);
  gemm_mfma<128, 128, false><<<nbG, 256, 0, stream>>>(
      (const short*)neighb, (const short*)hb, Wl, Wr, bl, (float*)d_out, nullptr,
      sums2, sumsq2);
  bn_final<<<1, 128, 0, stream>>>(sums2, sumsq2, g2, be2, scale2, shift2);
  bn_apply_f32<<<NN * FHID / 4 / 256, 256, 0, stream>>>((float*)d_out, scale2, shift2);
}

// Round 3
// 280.440 us; speedup vs baseline: 1.5857x; 1.2575x over previous
//
#include <hip/hip_runtime.h>

#define NN 50000
#define NE 600000
#define FIN 64
#define FHID 128
#define BN_EPS 1e-5f

typedef __attribute__((ext_vector_type(8))) short short8;
typedef __attribute__((ext_vector_type(4))) float f32x4;

// ---- bf16 helpers (finite inputs; RNE) ----
__device__ __forceinline__ unsigned short f2bf(float f) {
  unsigned u = __float_as_uint(f);
  return (unsigned short)((u + 0x7FFFu + ((u >> 16) & 1u)) >> 16);
}
__device__ __forceinline__ float bfs(unsigned short u) {
  return __uint_as_float(((unsigned)u) << 16);
}
__device__ __forceinline__ float bflo(unsigned v) { return __uint_as_float(v << 16); }
__device__ __forceinline__ float bfhi(unsigned v) { return __uint_as_float(v & 0xFFFF0000u); }

// ---------------- edge counting ----------------
__global__ __launch_bounds__(256) void count_kernel(const int* __restrict__ dst,
                                                    int* __restrict__ cnt) {
  int e = blockIdx.x * 256 + threadIdx.x;
  if (e < NE) atomicAdd(&cnt[dst[e]], 1);
}

// ---------------- exclusive scan over cnt (3 kernels) ----------------
__global__ __launch_bounds__(256) void scan1(const int* __restrict__ cnt,
                                             int* __restrict__ partial) {
  int i = blockIdx.x * 256 + threadIdx.x;
  int v = (i < NN) ? cnt[i] : 0;
  __shared__ int sh[256];
  sh[threadIdx.x] = v;
  __syncthreads();
  for (int off = 128; off > 0; off >>= 1) {
    if (threadIdx.x < off) sh[threadIdx.x] += sh[threadIdx.x + off];
    __syncthreads();
  }
  if (threadIdx.x == 0) partial[blockIdx.x] = sh[0];
}

__global__ __launch_bounds__(256) void scan2(int* __restrict__ partial, int nb) {
  __shared__ int sh[256];
  int t = threadIdx.x;
  sh[t] = (t < nb) ? partial[t] : 0;
  __syncthreads();
  for (int off = 1; off < 256; off <<= 1) {
    int v = (t >= off) ? sh[t - off] : 0;
    __syncthreads();
    sh[t] += v;
    __syncthreads();
  }
  partial[t] = (t == 0) ? 0 : sh[t - 1];  // exclusive
}

__global__ __launch_bounds__(256) void scan3(const int* __restrict__ cnt,
                                             const int* __restrict__ partial,
                                             int* __restrict__ rowptr,
                                             float* __restrict__ dis) {
  int i = blockIdx.x * 256 + threadIdx.x;
  int t = threadIdx.x;
  int v = (i < NN) ? cnt[i] : 0;
  __shared__ int sh[256];
  sh[t] = v;
  __syncthreads();
  for (int off = 1; off < 256; off <<= 1) {
    int u = (t >= off) ? sh[t - off] : 0;
    __syncthreads();
    sh[t] += u;
    __syncthreads();
  }
  if (i < NN) {
    rowptr[i] = partial[blockIdx.x] + (sh[t] - v);
    dis[i] = rsqrtf((float)(v + 1));  // deg = indeg + 1 (self loop)
  }
}

// ---------------- CSR bucket fill ----------------
__global__ __launch_bounds__(256) void fill_kernel(const int* __restrict__ src,
                                                   const int* __restrict__ dst,
                                                   const int* __restrict__ rowptr,
                                                   int* __restrict__ fill,
                                                   int* __restrict__ csr_src) {
  int e = blockIdx.x * 256 + threadIdx.x;
  if (e < NE) {
    int d = dst[e];
    int p = atomicAdd(&fill[d], 1);
    csr_src[rowptr[d] + p] = src[e];
  }
}

// ---------------- xs = dis[node] * x  (fp32 -> bf16 prescale) ----------------
__global__ __launch_bounds__(256) void scale_x(const float* __restrict__ x,
                                               const float* __restrict__ dis,
                                               ushort4* __restrict__ xs) {
  int i = blockIdx.x * 256 + threadIdx.x;  // float4 index; grid exact (800000)
  float4 v = ((const float4*)x)[i];
  float d = dis[i >> 4];  // 16 float4 per 64-wide row
  xs[i] = make_ushort4(f2bf(v.x * d), f2bf(v.y * d), f2bf(v.z * d), f2bf(v.w * d));
}

// ---------------- GCN aggregation: xa = di*(xs[node] + sum_e xs[src]) -------
// one wave per node; 8/4/1-unrolled independent gathers for MLP
__global__ __launch_bounds__(256) void gcn_agg(const unsigned short* __restrict__ xs,
                                               const int* __restrict__ csr_src,
                                               const int* __restrict__ rowptr,
                                               const int* __restrict__ cnt,
                                               const float* __restrict__ dis,
                                               unsigned short* __restrict__ xa) {
  int node = blockIdx.x * 4 + threadIdx.y;
  int lane = threadIdx.x;
  float di = dis[node];
  float acc = bfs(xs[node * FIN + lane]);  // self loop: di * (di*x_node)
  int e = rowptr[node];
  int end = e + cnt[node];
  for (; e + 8 <= end; e += 8) {
    int s0 = csr_src[e + 0], s1 = csr_src[e + 1], s2 = csr_src[e + 2],
        s3 = csr_src[e + 3], s4 = csr_src[e + 4], s5 = csr_src[e + 5],
        s6 = csr_src[e + 6], s7 = csr_src[e + 7];
    float a0 = bfs(xs[s0 * FIN + lane]), a1 = bfs(xs[s1 * FIN + lane]);
    float a2 = bfs(xs[s2 * FIN + lane]), a3 = bfs(xs[s3 * FIN + lane]);
    float a4 = bfs(xs[s4 * FIN + lane]), a5 = bfs(xs[s5 * FIN + lane]);
    float a6 = bfs(xs[s6 * FIN + lane]), a7 = bfs(xs[s7 * FIN + lane]);
    acc += ((a0 + a1) + (a2 + a3)) + ((a4 + a5) + (a6 + a7));
  }
  for (; e + 4 <= end; e += 4) {
    int s0 = csr_src[e + 0], s1 = csr_src[e + 1], s2 = csr_src[e + 2],
        s3 = csr_src[e + 3];
    float a0 = bfs(xs[s0 * FIN + lane]), a1 = bfs(xs[s1 * FIN + lane]);
    float a2 = bfs(xs[s2 * FIN + lane]), a3 = bfs(xs[s3 * FIN + lane]);
    acc += (a0 + a1) + (a2 + a3);
  }
  for (; e < end; ++e) acc += bfs(xs[csr_src[e] * FIN + lane]);
  xa[node * FIN + lane] = f2bf(di * acc);
}

// ---------------- SAGE mean aggregation on bf16 h (128 feats) ---------------
__global__ __launch_bounds__(256) void sage_agg(const unsigned* __restrict__ hb,
                                                const int* __restrict__ csr_src,
                                                const int* __restrict__ rowptr,
                                                const int* __restrict__ cnt,
                                                unsigned* __restrict__ neighb) {
  int node = blockIdx.x * 4 + threadIdx.y;
  int lane = threadIdx.x;  // 2 feats per lane (1 uint = 2 bf16)
  float ax = 0.f, ay = 0.f;
  int num = cnt[node];
  int e = rowptr[node];
  int end = e + num;
  for (; e + 8 <= end; e += 8) {
    int s0 = csr_src[e + 0], s1 = csr_src[e + 1], s2 = csr_src[e + 2],
        s3 = csr_src[e + 3], s4 = csr_src[e + 4], s5 = csr_src[e + 5],
        s6 = csr_src[e + 6], s7 = csr_src[e + 7];
    unsigned v0 = hb[s0 * 64 + lane], v1 = hb[s1 * 64 + lane];
    unsigned v2 = hb[s2 * 64 + lane], v3 = hb[s3 * 64 + lane];
    unsigned v4 = hb[s4 * 64 + lane], v5 = hb[s5 * 64 + lane];
    unsigned v6 = hb[s6 * 64 + lane], v7 = hb[s7 * 64 + lane];
    ax += ((bflo(v0) + bflo(v1)) + (bflo(v2) + bflo(v3))) +
          ((bflo(v4) + bflo(v5)) + (bflo(v6) + bflo(v7)));
    ay += ((bfhi(v0) + bfhi(v1)) + (bfhi(v2) + bfhi(v3))) +
          ((bfhi(v4) + bfhi(v5)) + (bfhi(v6) + bfhi(v7)));
  }
  for (; e + 4 <= end; e += 4) {
    int s0 = csr_src[e + 0], s1 = csr_src[e + 1], s2 = csr_src[e + 2],
        s3 = csr_src[e + 3];
    unsigned v0 = hb[s0 * 64 + lane], v1 = hb[s1 * 64 + lane];
    unsigned v2 = hb[s2 * 64 + lane], v3 = hb[s3 * 64 + lane];
    ax += (bflo(v0) + bflo(v1)) + (bflo(v2) + bflo(v3));
    ay += (bfhi(v0) + bfhi(v1)) + (bfhi(v2) + bfhi(v3));
  }
  for (; e < end; ++e) {
    unsigned v = hb[csr_src[e] * 64 + lane];
    ax += bflo(v);
    ay += bfhi(v);
  }
  float inv = 1.0f / fmaxf((float)num, 1.0f);
  neighb[node * 64 + lane] =
      (unsigned)f2bf(ax * inv) | ((unsigned)f2bf(ay * inv) << 16);
}

// ---------------- MFMA bf16 GEMM, fused bias + BN column stats --------------
template <int K1, int K2, bool OUTBF>
__global__ __launch_bounds__(256) void gemm_mfma(const short* __restrict__ A1,
                                                 const short* __restrict__ A2,
                                                 const float* __restrict__ B1,
                                                 const float* __restrict__ B2,
                                                 const float* __restrict__ bias,
                                                 float* __restrict__ Cf,
                                                 unsigned short* __restrict__ Cb,
                                                 float* __restrict__ sums,
                                                 float* __restrict__ sumsq) {
  constexpr int KT = K1 + K2;
  __shared__ short Bt[128][KT + 8];
  __shared__ float lsum[128], lsq[128];
  int tid = threadIdx.x;
  if (tid < 128) { lsum[tid] = 0.f; lsq[tid] = 0.f; }
  for (int idx = tid; idx < KT * 128; idx += 256) {
    int k = idx >> 7, n = idx & 127;
    float wv = (K2 == 0 || k < K1) ? B1[k * 128 + n] : B2[(k - K1) * 128 + n];
    Bt[n][k] = (short)f2bf(wv);
  }
  __syncthreads();

  int lane = tid & 63;
  int w = tid >> 6;
  int r = lane & 15;
  int q = lane >> 4;
  int row_base = blockIdx.x * 128 + w * 32;

  f32x4 acc[2][8];
#pragma unroll
  for (int m = 0; m < 2; ++m)
#pragma unroll
    for (int n = 0; n < 8; ++n) acc[m][n] = (f32x4){0.f, 0.f, 0.f, 0.f};

#pragma unroll
  for (int seg = 0; seg < 2; ++seg) {
    const int K = seg ? K2 : K1;
    if (K == 0) continue;
    const short* A = seg ? A2 : A1;
    const int kb = seg ? K1 : 0;
    for (int ks = 0; ks < K; ks += 32) {
      int row0 = row_base + r;
      int row1 = row_base + 16 + r;
      row0 = row0 < NN ? row0 : NN - 1;  // clamp: garbage rows never stored
      row1 = row1 < NN ? row1 : NN - 1;
      short8 af0 = *(const short8*)(A + (size_t)row0 * K + ks + q * 8);
      short8 af1 = *(const short8*)(A + (size_t)row1 * K + ks + q * 8);
#pragma unroll
      for (int n = 0; n < 8; ++n) {
        short8 bf = *(const short8*)(&Bt[n * 16 + r][kb + ks + q * 8]);
        acc[0][n] = __builtin_amdgcn_mfma_f32_16x16x32_bf16(af0, bf, acc[0][n], 0, 0, 0);
        acc[1][n] = __builtin_amdgcn_mfma_f32_16x16x32_bf16(af1, bf, acc[1][n], 0, 0, 0);
      }
    }
  }

  float bias_r[8];
#pragma unroll
  for (int n = 0; n < 8; ++n) bias_r[n] = bias[n * 16 + r];
  float cs[8], cq[8];
#pragma unroll
  for (int n = 0; n < 8; ++n) { cs[n] = 0.f; cq[n] = 0.f; }
#pragma unroll
  for (int m = 0; m < 2; ++m)
#pragma unroll
    for (int i = 0; i < 4; ++i) {
      int row = row_base + m * 16 + q * 4 + i;
      if (row < NN) {
#pragma unroll
        for (int n = 0; n < 8; ++n) {
          float v = acc[m][n][i] + bias_r[n];
          int col = n * 16 + r;
          if constexpr (OUTBF)
            Cb[(size_t)row * 128 + col] = f2bf(v);
          else
            Cf[(size_t)row * 128 + col] = v;
          cs[n] += v;
          cq[n] += v * v;
        }
      }
    }
#pragma unroll
  for (int n = 0; n < 8; ++n) {
    atomicAdd(&lsum[n * 16 + r], cs[n]);
    atomicAdd(&lsq[n * 16 + r], cq[n]);
  }
  __syncthreads();
  if (tid < 128) {
    atomicAdd(&sums[tid], lsum[tid]);
    atomicAdd(&sumsq[tid], lsq[tid]);
  }
}

// ---------------- BN finalize (in-block) + apply + ReLU, bf16 in-place ------
__global__ __launch_bounds__(256) void bn_apply_bf(unsigned* __restrict__ hb,
                                                   const float* __restrict__ sums,
                                                   const float* __restrict__ sumsq,
                                                   const float* __restrict__ gamma,
                                                   const float* __restrict__ beta) {
  __shared__ float sc[128], sh[128];
  int t = threadIdx.x;
  if (t < 128) {
    float mean = sums[t] * (1.0f / NN);
    float var = fmaxf(sumsq[t] * (1.0f / NN) - mean * mean, 0.f);
    float inv = rsqrtf(var + BN_EPS);
    float s = gamma[t] * inv;
    sc[t] = s;
    sh[t] = beta[t] - mean * s;
  }
  __syncthreads();
  int i = blockIdx.x * 256 + t;  // uint2 index; grid exact
  uint2 v = ((uint2*)hb)[i];
  int c = (i & 31) * 4;
  float f0 = fmaxf(fmaf(bflo(v.x), sc[c + 0], sh[c + 0]), 0.f);
  float f1 = fmaxf(fmaf(bfhi(v.x), sc[c + 1], sh[c + 1]), 0.f);
  float f2 = fmaxf(fmaf(bflo(v.y), sc[c + 2], sh[c + 2]), 0.f);
  float f3 = fmaxf(fmaf(bfhi(v.y), sc[c + 3], sh[c + 3]), 0.f);
  v.x = (unsigned)f2bf(f0) | ((unsigned)f2bf(f1) << 16);
  v.y = (unsigned)f2bf(f2) | ((unsigned)f2bf(f3) << 16);
  ((uint2*)hb)[i] = v;
}

// ---------------- BN finalize (in-block) + apply + ReLU, fp32 in-place ------
__global__ __launch_bounds__(256) void bn_apply_f32(float* __restrict__ out,
                                                    const float* __restrict__ sums,
                                                    const float* __restrict__ sumsq,
                                                    const float* __restrict__ gamma,
                                                    const float* __restrict__ beta) {
  __shared__ float sc[128], sh[128];
  int t = threadIdx.x;
  if (t < 128) {
    float mean = sums[t] * (1.0f / NN);
    float var = fmaxf(sumsq[t] * (1.0f / NN) - mean * mean, 0.f);
    float inv = rsqrtf(var + BN_EPS);
    float s = gamma[t] * inv;
    sc[t] = s;
    sh[t] = beta[t] - mean * s;
  }
  __syncthreads();
  int i4 = blockIdx.x * 256 + t;  // float4 index; grid exact
  float4 v = ((const float4*)out)[i4];
  int f = (i4 & 31) * 4;
  v.x = fmaxf(fmaf(v.x, sc[f + 0], sh[f + 0]), 0.f);
  v.y = fmaxf(fmaf(v.y, sc[f + 1], sh[f + 1]), 0.f);
  v.z = fmaxf(fmaf(v.z, sc[f + 2], sh[f + 2]), 0.f);
  v.w = fmaxf(fmaf(v.w, sc[f + 3], sh[f + 3]), 0.f);
  ((float4*)out)[i4] = v;
}

extern "C" void kernel_launch(void* const* d_in, const int* in_sizes, int n_in,
                              void* d_out, int out_size, void* d_ws, size_t ws_size,
                              hipStream_t stream) {
  const float* x   = (const float*)d_in[0];
  const int*   ei  = (const int*)d_in[1];
  const float* W1  = (const float*)d_in[2];
  const float* b1  = (const float*)d_in[3];
  const float* g1  = (const float*)d_in[4];
  const float* be1 = (const float*)d_in[5];
  const float* Wl  = (const float*)d_in[6];
  const float* bl  = (const float*)d_in[7];
  const float* Wr  = (const float*)d_in[8];
  const float* g2  = (const float*)d_in[9];
  const float* be2 = (const float*)d_in[10];
  const int* srcp = ei;
  const int* dstp = ei + NE;

  char* w = (char*)d_ws;
  auto alloc = [&](size_t bytes) {
    char* p = w;
    w += (bytes + 255) & ~(size_t)255;
    return p;
  };
  int*   cnt     = (int*)alloc((size_t)NN * 4);
  int*   fill    = (int*)alloc((size_t)NN * 4);
  int*   rowptr  = (int*)alloc((size_t)NN * 4);
  int*   partial = (int*)alloc(256 * 4);
  float* dis     = (float*)alloc((size_t)NN * 4);
  int*   csr     = (int*)alloc((size_t)NE * 4);
  unsigned short* xs     = (unsigned short*)alloc((size_t)NN * FIN * 2);
  unsigned short* xa     = (unsigned short*)alloc((size_t)NN * FIN * 2);
  unsigned short* hb     = (unsigned short*)alloc((size_t)NN * FHID * 2);
  unsigned*       neighb = (unsigned*)alloc((size_t)NN * FHID * 2);
  float* stats   = (float*)alloc(8 * 128 * 4);
  float* sums1 = stats,       *sumsq1 = stats + 128;
  float* sums2 = stats + 512, *sumsq2 = stats + 640;

  hipMemsetAsync(cnt, 0, (size_t)NN * 4, stream);
  hipMemsetAsync(fill, 0, (size_t)NN * 4, stream);
  hipMemsetAsync(stats, 0, 8 * 128 * 4, stream);

  int nbE = (NE + 255) / 256;
  int nbN = (NN + 255) / 256;  // 196 <= 256 (scan2 single-block limit)
  int nbG = (NN + 127) / 128;  // 391 MFMA blocks

  count_kernel<<<nbE, 256, 0, stream>>>(dstp, cnt);
  scan1<<<nbN, 256, 0, stream>>>(cnt, partial);
  scan2<<<1, 256, 0, stream>>>(partial, nbN);
  scan3<<<nbN, 256, 0, stream>>>(cnt, partial, rowptr, dis);
  fill_kernel<<<nbE, 256, 0, stream>>>(srcp, dstp, rowptr, fill, csr);
  scale_x<<<NN * FIN / 4 / 256, 256, 0, stream>>>(x, dis, (ushort4*)xs);

  // GCN: aggregate prescaled bf16 X, MFMA GEMM K=64 -> bf16 h
  gcn_agg<<<NN / 4, dim3(64, 4), 0, stream>>>(xs, csr, rowptr, cnt, dis, xa);
  gemm_mfma<64, 0, true><<<nbG, 256, 0, stream>>>(
      (const short*)xa, nullptr, W1, nullptr, b1, nullptr, hb, sums1, sumsq1);
  bn_apply_bf<<<NN * FHID / 4 / 256, 256, 0, stream>>>((unsigned*)hb, sums1, sumsq1,
                                                       g1, be1);

  // SAGE: mean-agg bf16 h, fused K=256 MFMA GEMM -> fp32 d_out
  sage_agg<<<NN / 4, dim3(64, 4), 0, stream>>>((const unsigned*)hb, csr, rowptr, cnt,
                                               neighb);
  gemm_mfma<128, 128, false><<<nbG, 256, 0, stream>>>(
      (const short*)neighb, (const short*)hb, Wl, Wr, bl, (float*)d_out, nullptr,
      sums2, sumsq2);
  bn_apply_f32<<<NN * FHID / 4 / 256, 256, 0, stream>>>((float*)d_out, sums2, sumsq2,
                                                        g2, be2);
}